// Round 8
// baseline (574.074 us; speedup 1.0000x reference)
//
#include <hip/hip_runtime.h>
#include <hip/hip_cooperative_groups.h>

// ---------------------------------------------------------------------------
// MambaBlock fused pipeline, MI355X (gfx950) — round 8
// B=2, L=1024, D_MODEL=1024, D_INNER=2048, D_STATE=16, D_CONV=4, DT_RANK=64
//
// Theory: dispatch count is the dominant tax (~10 µs/launch; 14->333, 11->280,
// 9->263). Changes vs round 7: conv + skinny-GEMM + delta-GEMM + scan1/2/3
// fused into ONE cooperative kernel (512 blocks x 256 thr, 2 blocks/CU,
// grid.sync() between phases). 9 -> 4 launches. Phase bodies identical to
// round 7 (same arithmetic -> same absmax).
// ---------------------------------------------------------------------------

namespace cg = cooperative_groups;

typedef unsigned short u16;
typedef unsigned int   u32;

#define B_SZ 2
#define L_SZ 1024
#define DM   1024
#define DI   2048
#define DS   16
#define DTR  64
#define NXD  96      /* DTR + 2*DS */
#define NCHUNK 32
#define CL   32      /* chunk length: NCHUNK*CL = L */
#define KSPLIT 8     /* split-K for skinny x_dbl GEMM */
#define KC     256   /* 2048 / KSPLIT */

typedef __bf16 bf16x8 __attribute__((ext_vector_type(8)));
typedef float  f32x4  __attribute__((ext_vector_type(4)));

__device__ __forceinline__ u16 f2bf(float f) {
    u32 x = __float_as_uint(f);
    x += 0x7fffu + ((x >> 16) & 1u);   // round-to-nearest-even
    return (u16)(x >> 16);
}
__device__ __forceinline__ float bf2f(u16 v) {
    return __uint_as_float(((u32)v) << 16);
}

__device__ __forceinline__ void gld_lds16(const u16* g, u16* l) {
    __builtin_amdgcn_global_load_lds(
        (const __attribute__((address_space(1))) u32*)g,
        (__attribute__((address_space(3))) u32*)l, 16, 0, 0);
}

// raw workgroup barrier WITHOUT the compiler's vmcnt(0) drain
__device__ __forceinline__ void wg_barrier() {
    __asm__ volatile("" ::: "memory");
    __builtin_amdgcn_s_barrier();
    __asm__ volatile("" ::: "memory");
}
#define WAIT_VM12() __builtin_amdgcn_s_waitcnt(0xF7C)
#define WAIT_VM9()  __builtin_amdgcn_s_waitcnt(0xF79)
#define WAIT_VM8()  __builtin_amdgcn_s_waitcnt(0xF78)
#define WAIT_VM6()  __builtin_amdgcn_s_waitcnt(0xF76)
#define WAIT_VM4()  __builtin_amdgcn_s_waitcnt(0xF74)
#define WAIT_VM3()  __builtin_amdgcn_s_waitcnt(0xF73)
#define WAIT_VM0()  __builtin_amdgcn_s_waitcnt(0xF70)
#define WAIT_LGKM0() __builtin_amdgcn_s_waitcnt(0x070F)

// ---------------------------------------------------------------------------
// Pipelined 128x128 GEMM (proven): C = A[M,K]*BT[N,K]^T, BK=32, 4-buf ring,
// prefetch distance 3. op==2: Cb bf16 out.
// ---------------------------------------------------------------------------
__global__ __launch_bounds__(256) void gemm128p(
    const u16* __restrict__ A, const u16* __restrict__ BT,
    float* __restrict__ Cf, u16* __restrict__ Cb,
    int M, int N, int K, int op)
{
    __shared__ u16 As[4][128 * 32];
    __shared__ u16 Bs[4][128 * 32];

    const int tid  = threadIdx.x;
    const int wave = tid >> 6;
    const int lane = tid & 63;
    const int q    = lane >> 4;
    const int r16  = lane & 15;
    const int wm   = (wave & 1) * 64;
    const int wn   = (wave >> 1) * 64;
    const int m0   = blockIdx.y * 128;
    const int n0   = blockIdx.x * 128;

    const u16* gA0 = A  + (size_t)(m0 + (tid >> 2))      * K + (tid & 3) * 8;
    const u16* gA1 = A  + (size_t)(m0 + 64 + (tid >> 2)) * K + (tid & 3) * 8;
    const u16* gB0 = BT + (size_t)(n0 + (tid >> 2))      * K + (tid & 3) * 8;
    const u16* gB1 = BT + (size_t)(n0 + 64 + (tid >> 2)) * K + (tid & 3) * 8;

    const int niter = K >> 5;
    const int pre = niter < 3 ? niter : 3;
    for (int p = 0; p < pre; ++p) {
        const int k0 = p * 32;
        gld_lds16(gA0 + k0, &As[p][tid * 8]);
        gld_lds16(gA1 + k0, &As[p][2048 + tid * 8]);
        gld_lds16(gB0 + k0, &Bs[p][tid * 8]);
        gld_lds16(gB1 + k0, &Bs[p][2048 + tid * 8]);
    }

    f32x4 acc[4][4];
#pragma unroll
    for (int s = 0; s < 4; ++s)
#pragma unroll
        for (int j = 0; j < 4; ++j) acc[s][j] = (f32x4){0.f, 0.f, 0.f, 0.f};

    for (int it = 0; it < niter; ++it) {
        if (it + 3 < niter) {
            const int k0 = (it + 3) * 32;
            const int bi = (it + 3) & 3;
            gld_lds16(gA0 + k0, &As[bi][tid * 8]);
            gld_lds16(gA1 + k0, &As[bi][2048 + tid * 8]);
            gld_lds16(gB0 + k0, &Bs[bi][tid * 8]);
            gld_lds16(gB1 + k0, &Bs[bi][2048 + tid * 8]);
            WAIT_VM12();
        } else if (it + 2 < niter) {
            WAIT_VM8();
        } else if (it + 1 < niter) {
            WAIT_VM4();
        } else {
            WAIT_VM0();
        }
        wg_barrier();

        const int cur = it & 3;
        bf16x8 af[4], bfr[4];
#pragma unroll
        for (int s = 0; s < 4; ++s)
            af[s] = *(const bf16x8*)(&As[cur][(wm + s * 16 + r16) * 32 + q * 8]);
#pragma unroll
        for (int j = 0; j < 4; ++j)
            bfr[j] = *(const bf16x8*)(&Bs[cur][(wn + j * 16 + r16) * 32 + q * 8]);
#pragma unroll
        for (int s = 0; s < 4; ++s)
#pragma unroll
            for (int j = 0; j < 4; ++j)
                acc[s][j] = __builtin_amdgcn_mfma_f32_16x16x32_bf16(
                    af[s], bfr[j], acc[s][j], 0, 0, 0);

        wg_barrier();
    }

#pragma unroll
    for (int s = 0; s < 4; ++s) {
        const int row0 = m0 + wm + s * 16 + q * 4;
#pragma unroll
        for (int j = 0; j < 4; ++j) {
            const int col = n0 + wn + j * 16 + r16;
            if (op == 2) {
#pragma unroll
                for (int i = 0; i < 4; ++i)
                    Cb[(size_t)(row0 + i) * N + col] = f2bf(acc[s][j][i]);
            } else {
#pragma unroll
                for (int i = 0; i < 4; ++i)
                    Cf[(size_t)(row0 + i) * N + col] = acc[s][j][i];
            }
        }
    }
}

// ---------------------------------------------------------------------------
// GEMM-out (proven round 7): 128x64 tile, no split-K, direct fp32.
// ---------------------------------------------------------------------------
__global__ __launch_bounds__(256) void gemm_out64(
    const u16* __restrict__ A, const u16* __restrict__ BT,
    float* __restrict__ C, int M, int N, int K)
{
    __shared__ u16 As[4][128 * 32];
    __shared__ u16 Bs[4][64 * 32];

    const int tid  = threadIdx.x;
    const int wave = tid >> 6;
    const int lane = tid & 63;
    const int q    = lane >> 4;
    const int r16  = lane & 15;
    const int wm   = (wave & 1) * 64;
    const int wn   = (wave >> 1) * 32;
    const int m0   = blockIdx.y * 128;
    const int n0   = blockIdx.x * 64;

    const u16* gA0 = A  + (size_t)(m0 + (tid >> 2))      * K + (tid & 3) * 8;
    const u16* gA1 = A  + (size_t)(m0 + 64 + (tid >> 2)) * K + (tid & 3) * 8;
    const u16* gB0 = BT + (size_t)(n0 + (tid >> 2))      * K + (tid & 3) * 8;

    const int niter = K >> 5;
    const int pre = niter < 3 ? niter : 3;
    for (int p = 0; p < pre; ++p) {
        const int k0 = p * 32;
        gld_lds16(gA0 + k0, &As[p][tid * 8]);
        gld_lds16(gA1 + k0, &As[p][2048 + tid * 8]);
        gld_lds16(gB0 + k0, &Bs[p][tid * 8]);
    }

    f32x4 acc[4][2];
#pragma unroll
    for (int s = 0; s < 4; ++s)
#pragma unroll
        for (int j = 0; j < 2; ++j) acc[s][j] = (f32x4){0.f, 0.f, 0.f, 0.f};

    for (int it = 0; it < niter; ++it) {
        if (it + 3 < niter) {
            const int k0 = (it + 3) * 32;
            const int bi = (it + 3) & 3;
            gld_lds16(gA0 + k0, &As[bi][tid * 8]);
            gld_lds16(gA1 + k0, &As[bi][2048 + tid * 8]);
            gld_lds16(gB0 + k0, &Bs[bi][tid * 8]);
            WAIT_VM9();
        } else if (it + 2 < niter) {
            WAIT_VM6();
        } else if (it + 1 < niter) {
            WAIT_VM3();
        } else {
            WAIT_VM0();
        }
        wg_barrier();

        const int cur = it & 3;
        bf16x8 af[4], bfr[2];
#pragma unroll
        for (int s = 0; s < 4; ++s)
            af[s] = *(const bf16x8*)(&As[cur][(wm + s * 16 + r16) * 32 + q * 8]);
#pragma unroll
        for (int j = 0; j < 2; ++j)
            bfr[j] = *(const bf16x8*)(&Bs[cur][(wn + j * 16 + r16) * 32 + q * 8]);
#pragma unroll
        for (int s = 0; s < 4; ++s)
#pragma unroll
            for (int j = 0; j < 2; ++j)
                acc[s][j] = __builtin_amdgcn_mfma_f32_16x16x32_bf16(
                    af[s], bfr[j], acc[s][j], 0, 0, 0);

        wg_barrier();
    }

#pragma unroll
    for (int s = 0; s < 4; ++s) {
        const int row0 = m0 + wm + s * 16 + q * 4;
#pragma unroll
        for (int j = 0; j < 2; ++j) {
            const int col = n0 + wn + j * 16 + r16;
#pragma unroll
            for (int i = 0; i < 4; ++i)
                C[(size_t)(row0 + i) * N + col] = acc[s][j][i];
        }
    }
}

// ---------------------------------------------------------------------------
// fused prep: x cast + 4 weight transposes + zero xdbl (for atomics)
// ---------------------------------------------------------------------------
__device__ __forceinline__ void tr_tile(
    const float* __restrict__ in, u16* __restrict__ out,
    int R, int C, int tr, int tc, int tid, float (*t)[33])
{
    const int tx = tid & 31, ty = tid >> 5;
    const int r0 = tr * 32, c0 = tc * 32;
#pragma unroll
    for (int i = 0; i < 4; ++i) {
        int r = r0 + ty + i * 8, c = c0 + tx;
        if (r < R && c < C) t[ty + i * 8][tx] = in[(size_t)r * C + c];
    }
    __syncthreads();
#pragma unroll
    for (int i = 0; i < 4; ++i) {
        int oR = c0 + ty + i * 8, oC = r0 + tx;
        if (oR < C && oC < R) out[(size_t)oR * R + oC] = f2bf(t[tx][ty + i * 8]);
    }
}

__global__ __launch_bounds__(256) void prep_kernel(
    const float* __restrict__ x,     u16* __restrict__ xbf,
    const float* __restrict__ W_in,  u16* __restrict__ winT,
    const float* __restrict__ W_out, u16* __restrict__ woutT,
    const float* __restrict__ W_x,   u16* __restrict__ wxT,
    const float* __restrict__ W_dt,  u16* __restrict__ wdtT,
    float* __restrict__ xdbl)
{
    __shared__ float t[32][33];
    const int id  = blockIdx.x;
    const int tid = threadIdx.x;
    if (id < 4096) {                                   // W_in: 1024x4096
        tr_tile(W_in, winT, 1024, 4096, id >> 7, id & 127, tid, t);
    } else if (id < 6144) {                            // W_out: 2048x1024
        int i2 = id - 4096;
        tr_tile(W_out, woutT, 2048, 1024, i2 >> 5, i2 & 31, tid, t);
    } else if (id < 6336) {                            // W_x: 2048x96
        int i3 = id - 6144;
        tr_tile(W_x, wxT, 2048, 96, i3 / 3, i3 % 3, tid, t);
    } else if (id < 6464) {                            // W_dt: 64x2048
        int i4 = id - 6336;
        tr_tile(W_dt, wdtT, 64, 2048, i4 >> 6, i4 & 63, tid, t);
    } else if (id < 14656) {                           // x cast: 2,097,152
        int i = (id - 6464) * 256 + tid;
        xbf[i] = f2bf(x[i]);
    } else {                                           // zero xdbl: 196,608 f
        f32x4 z = (f32x4){0.f, 0.f, 0.f, 0.f};
        ((f32x4*)xdbl)[(size_t)(id - 14656) * 256 + tid] = z;
    }
}

// ---------------------------------------------------------------------------
// MEGA cooperative kernel: conv+silu | skinny GEMM (atomic) | delta GEMM |
// scan1 | scan2 | scan3 — separated by grid.sync(). 512 blocks x 256 thr,
// 2 blocks/CU guaranteed by __launch_bounds__(256, 2).
// ---------------------------------------------------------------------------
__global__ __launch_bounds__(256, 2) void mega_kernel(
    const u16* __restrict__ xzbf, const float* __restrict__ cw,
    const float* __restrict__ cb, u16* __restrict__ ucbf,
    const u16* __restrict__ wxT, float* __restrict__ xdbl,
    const u16* __restrict__ wdtT, const float* __restrict__ b_dt,
    float* __restrict__ dlt,
    const float* __restrict__ A_log, const float* __restrict__ Dsk,
    float* __restrict__ hbuf, float* __restrict__ pbuf,
    u16* __restrict__ ybf)
{
    cg::grid_group grid = cg::this_grid();
    const int bid = blockIdx.x;
    const int tid = threadIdx.x;

    constexpr int LDT = 40;
    __shared__ u16 As[128 * LDT];
    __shared__ u16 Bs[64 * LDT];

    // ---- phase 1: causal conv + bias + silu (grid-stride) ----
    for (int idx = bid * 256 + tid; idx < B_SZ * L_SZ * DI; idx += 512 * 256) {
        const int d   = idx & (DI - 1);
        const int pos = idx >> 11;
        const int l   = pos & (L_SZ - 1);
        float s = cb[d];
#pragma unroll
        for (int k = 0; k < 4; ++k) {
            int ls = l + k - 3;
            if (ls >= 0)
                s = fmaf(bf2f(xzbf[(size_t)(pos + k - 3) * (2 * DI) + d]), cw[d * 4 + k], s);
        }
        float v = s / (1.f + __expf(-s));
        ucbf[idx] = f2bf(v);
    }
    grid.sync();

    // ---- phase 2: skinny GEMM u @ W_x -> atomicAdd xdbl (blocks 0..255) ----
    if (bid < 256) {
        const int wave = tid >> 6, lane = tid & 63;
        const int q = lane >> 4, r16 = lane & 15;
        const int n0  = (bid & 1) * 64;
        const int m0  = ((bid >> 1) & 15) * 128;
        const int kcs = (bid >> 5) * KC;
        const int sr  = tid >> 2, ss = (tid & 3) * 8;

        f32x4 acc[2][4];
#pragma unroll
        for (int s = 0; s < 2; ++s)
#pragma unroll
            for (int j = 0; j < 4; ++j) acc[s][j] = (f32x4){0.f, 0.f, 0.f, 0.f};

        const int bcol  = n0 + sr;
        const int bcolc = bcol < NXD ? bcol : NXD - 1;

        constexpr int NIT = KC / 32;
        uint4 a0 = *(const uint4*)(ucbf + (size_t)(m0 + sr)      * DI + kcs + ss);
        uint4 a1 = *(const uint4*)(ucbf + (size_t)(m0 + 64 + sr) * DI + kcs + ss);
        uint4 bv = *(const uint4*)(wxT + (size_t)bcolc * DI + kcs + ss);

        for (int it = 0; it < NIT; ++it) {
            wg_barrier();
            *(uint4*)(As + sr * LDT + ss)        = a0;
            *(uint4*)(As + (64 + sr) * LDT + ss) = a1;
            *(uint4*)(Bs + sr * LDT + ss)        = bv;
            const int kn = (it + 1 < NIT) ? (kcs + (it + 1) * 32) : kcs;
            a0 = *(const uint4*)(ucbf + (size_t)(m0 + sr)      * DI + kn + ss);
            a1 = *(const uint4*)(ucbf + (size_t)(m0 + 64 + sr) * DI + kn + ss);
            bv = *(const uint4*)(wxT + (size_t)bcolc * DI + kn + ss);
            WAIT_LGKM0();
            wg_barrier();

            bf16x8 af[2], bfr[4];
#pragma unroll
            for (int s = 0; s < 2; ++s)
                af[s] = *(const bf16x8*)(As + (wave * 32 + s * 16 + r16) * LDT + q * 8);
#pragma unroll
            for (int j = 0; j < 4; ++j)
                bfr[j] = *(const bf16x8*)(Bs + (j * 16 + r16) * LDT + q * 8);
#pragma unroll
            for (int s = 0; s < 2; ++s)
#pragma unroll
                for (int j = 0; j < 4; ++j)
                    acc[s][j] = __builtin_amdgcn_mfma_f32_16x16x32_bf16(
                        af[s], bfr[j], acc[s][j], 0, 0, 0);
        }

#pragma unroll
        for (int s = 0; s < 2; ++s) {
            const int row0 = m0 + wave * 32 + s * 16 + q * 4;
#pragma unroll
            for (int j = 0; j < 4; ++j) {
                const int col = n0 + j * 16 + r16;
                if (col < NXD) {
#pragma unroll
                    for (int i = 0; i < 4; ++i)
                        atomicAdd(&xdbl[(size_t)(row0 + i) * NXD + col], acc[s][j][i]);
                }
            }
        }
    }
    grid.sync();

    // ---- phase 3: delta GEMM softplus(xdbl[:,:64] @ W_dt + b_dt) ----
    {
        const int wave = tid >> 6, lane = tid & 63;
        const int q = lane >> 4, r16 = lane & 15;
        const int wm = (wave & 1) * 64, wn = (wave >> 1) * 32;
        const int n0 = (bid & 31) * 64;
        const int m0 = (bid >> 5) * 128;
        const int sr = tid >> 2, ss = (tid & 3) * 8;

        f32x4 acc[4][2];
#pragma unroll
        for (int s = 0; s < 4; ++s)
#pragma unroll
            for (int j = 0; j < 2; ++j) acc[s][j] = (f32x4){0.f, 0.f, 0.f, 0.f};

        for (int k0 = 0; k0 < DTR; k0 += 32) {
            __syncthreads();
            f32x4 f0 = *(const f32x4*)(xdbl + (size_t)(m0 + sr) * NXD + k0 + ss);
            f32x4 f1 = *(const f32x4*)(xdbl + (size_t)(m0 + sr) * NXD + k0 + ss + 4);
            f32x4 f2 = *(const f32x4*)(xdbl + (size_t)(m0 + 64 + sr) * NXD + k0 + ss);
            f32x4 f3 = *(const f32x4*)(xdbl + (size_t)(m0 + 64 + sr) * NXD + k0 + ss + 4);
            uint4 bv0 = *(const uint4*)(wdtT + (size_t)(n0 + sr) * DTR + k0 + ss);
            u16* pa0 = As + sr * LDT + ss;
            u16* pa1 = As + (64 + sr) * LDT + ss;
#pragma unroll
            for (int i = 0; i < 4; ++i) { pa0[i] = f2bf(f0[i]); pa0[4 + i] = f2bf(f1[i]); }
#pragma unroll
            for (int i = 0; i < 4; ++i) { pa1[i] = f2bf(f2[i]); pa1[4 + i] = f2bf(f3[i]); }
            *(uint4*)(Bs + sr * LDT + ss) = bv0;
            __syncthreads();

            bf16x8 af[4], bfr[2];
#pragma unroll
            for (int s = 0; s < 4; ++s)
                af[s] = *(const bf16x8*)(As + (wm + s * 16 + r16) * LDT + q * 8);
#pragma unroll
            for (int j = 0; j < 2; ++j)
                bfr[j] = *(const bf16x8*)(Bs + (wn + j * 16 + r16) * LDT + q * 8);
#pragma unroll
            for (int s = 0; s < 4; ++s)
#pragma unroll
                for (int j = 0; j < 2; ++j)
                    acc[s][j] = __builtin_amdgcn_mfma_f32_16x16x32_bf16(
                        af[s], bfr[j], acc[s][j], 0, 0, 0);
        }

#pragma unroll
        for (int s = 0; s < 4; ++s) {
            const int row0 = m0 + wm + s * 16 + q * 4;
#pragma unroll
            for (int j = 0; j < 2; ++j) {
                const int col = n0 + wn + j * 16 + r16;
                const float bv = b_dt[col];
#pragma unroll
                for (int i = 0; i < 4; ++i) {
                    float v = acc[s][j][i] + bv;
                    v = (v > 20.f) ? v : log1pf(__expf(v));
                    dlt[(size_t)(row0 + i) * DI + col] = v;
                }
            }
        }
    }
    grid.sync();

    // ---- phase 4: scan pass 1 (local chunk scans) ----
    {
        const int c = bid & 31;
        const int r = bid >> 5;
        const int g = r & 7;
        const int b = r >> 3;
        const int d = g * 256 + tid;
        float Av[16], h[16], P[16];
#pragma unroll
        for (int n = 0; n < 16; ++n) {
            Av[n] = -__expf(A_log[d * 16 + n]);
            h[n] = 0.f; P[n] = 1.f;
        }
        const int rowbase = b * L_SZ + c * CL;
        for (int i = 0; i < CL; ++i) {
            const int row = rowbase + i;
            float dv = dlt[(size_t)row * DI + d];
            float uu = bf2f(ucbf[(size_t)row * DI + d]);
            float du = dv * uu;
            const float* xr = xdbl + (size_t)row * NXD;
#pragma unroll
            for (int n = 0; n < 16; ++n) {
                float e = __expf(dv * Av[n]);
                P[n] *= e;
                h[n] = fmaf(e, h[n], du * xr[DTR + n]);
            }
        }
        size_t base = ((size_t)((b * NCHUNK + c) * DI + d)) * 16;
#pragma unroll
        for (int n = 0; n < 16; ++n) { hbuf[base + n] = h[n]; pbuf[base + n] = P[n]; }
    }
    grid.sync();

    // ---- phase 5: scan pass 2 (chunk-carry stitch, coalesced) ----
    {
        const int tidg = bid * 256 + tid;
        if (tidg < 2 * DI * 16) {
            const int b = tidg >> 15;
            const int j = tidg & (DI * 16 - 1);
            float h0 = 0.f;
            for (int cc = 0; cc < NCHUNK; ++cc) {
                size_t o = ((size_t)(b * NCHUNK + cc)) * (DI * 16) + j;
                float hl = hbuf[o];
                float Pl = pbuf[o];
                hbuf[o] = h0;
                h0 = fmaf(Pl, h0, hl);
            }
        }
    }
    grid.sync();

    // ---- phase 6: scan pass 3 (replay + fused epilogue) ----
    {
        const int c = bid & 31;
        const int r = bid >> 5;
        const int g = r & 7;
        const int b = r >> 3;
        const int d = g * 256 + tid;
        float Av[16], h[16];
        size_t base = ((size_t)((b * NCHUNK + c) * DI + d)) * 16;
#pragma unroll
        for (int n = 0; n < 16; ++n) {
            Av[n] = -__expf(A_log[d * 16 + n]);
            h[n]  = hbuf[base + n];
        }
        const float Dk = Dsk[d];
        const int rowbase = b * L_SZ + c * CL;
        for (int i = 0; i < CL; ++i) {
            const int row = rowbase + i;
            float dv = dlt[(size_t)row * DI + d];
            float uu = bf2f(ucbf[(size_t)row * DI + d]);
            float du = dv * uu;
            const float* xr = xdbl + (size_t)row * NXD;
            float y = 0.f;
#pragma unroll
            for (int n = 0; n < 16; ++n) {
                float e = __expf(dv * Av[n]);
                h[n] = fmaf(e, h[n], du * xr[DTR + n]);
                y = fmaf(h[n], xr[DTR + DS + n], y);
            }
            float zz = bf2f(xzbf[(size_t)row * (2 * DI) + DI + d]);
            float yv = fmaf(uu, Dk, y) * (zz / (1.f + __expf(-zz)));
            ybf[(size_t)row * DI + d] = f2bf(yv);
        }
    }
}

// ---------------------------------------------------------------------------
// workspace layout (f32 element offsets)
// ---------------------------------------------------------------------------
constexpr size_t OFF_DELTA   = 0;                          // 4,194,304 f
constexpr size_t OFF_XDBL    = OFF_DELTA + 4194304;        //   196,608 f
constexpr size_t OFF_HBUF    = OFF_XDBL  + 196608;         // 2,097,152 f
constexpr size_t OFF_PBUF    = OFF_HBUF  + 2097152;        // 2,097,152 f
constexpr size_t OFF_F32_END = OFF_PBUF  + 2097152;
// bf16 region (u16 offsets from end of fp32 region)
constexpr size_t SOFF_XBF   = 0;                     // 2,097,152
constexpr size_t SOFF_WINT  = SOFF_XBF   + 2097152;  // 4,194,304
constexpr size_t SOFF_XZBF  = SOFF_WINT  + 4194304;  // 8,388,608
constexpr size_t SOFF_UCBF  = SOFF_XZBF  + 8388608;  // 4,194,304
constexpr size_t SOFF_WXT   = SOFF_UCBF  + 4194304;  //   196,608
constexpr size_t SOFF_WDTT  = SOFF_WXT   + 196608;   //   131,072
constexpr size_t SOFF_WOUTT = SOFF_WDTT  + 131072;   // 2,097,152
constexpr size_t SOFF_YBF   = SOFF_WOUTT + 2097152;  // 4,194,304

extern "C" void kernel_launch(void* const* d_in, const int* in_sizes, int n_in,
                              void* d_out, int out_size, void* d_ws, size_t ws_size,
                              hipStream_t stream)
{
    const float* x     = (const float*)d_in[0];
    const float* W_in  = (const float*)d_in[1];
    const float* cw    = (const float*)d_in[2];
    const float* cb    = (const float*)d_in[3];
    const float* W_x   = (const float*)d_in[4];
    const float* W_dt  = (const float*)d_in[5];
    const float* b_dt  = (const float*)d_in[6];
    const float* A_log = (const float*)d_in[7];
    const float* Dsk   = (const float*)d_in[8];
    const float* W_out = (const float*)d_in[9];
    float* out = (float*)d_out;

    float* wsf   = (float*)d_ws;
    float* dlt   = wsf + OFF_DELTA;
    float* xdbl  = wsf + OFF_XDBL;
    float* hbuf  = wsf + OFF_HBUF;
    float* pbuf  = wsf + OFF_PBUF;
    u16* sb    = (u16*)(wsf + OFF_F32_END);
    u16* xbf   = sb + SOFF_XBF;
    u16* winT  = sb + SOFF_WINT;
    u16* xzbf  = sb + SOFF_XZBF;
    u16* ucbf  = sb + SOFF_UCBF;
    u16* wxT   = sb + SOFF_WXT;
    u16* wdtT  = sb + SOFF_WDTT;
    u16* woutT = sb + SOFF_WOUTT;
    u16* ybf   = sb + SOFF_YBF;

    // 1) fused prep (casts, transposes, xdbl zero)
    prep_kernel<<<14848, 256, 0, stream>>>(x, xbf, W_in, winT, W_out, woutT,
                                           W_x, wxT, W_dt, wdtT, xdbl);

    // 2) xz = x @ W_in  (M=2048, N=4096, K=1024) -> bf16
    gemm128p<<<dim3(32, 16), 256, 0, stream>>>(
        xbf, winT, nullptr, xzbf, 2048, 4096, 1024, 2);

    // 3) MEGA cooperative: conv | skinny | delta | scan1 | scan2 | scan3
    {
        void* margs[] = {
            (void*)&xzbf, (void*)&cw, (void*)&cb, (void*)&ucbf,
            (void*)&wxT,  (void*)&xdbl,
            (void*)&wdtT, (void*)&b_dt, (void*)&dlt,
            (void*)&A_log, (void*)&Dsk,
            (void*)&hbuf, (void*)&pbuf, (void*)&ybf
        };
        hipLaunchCooperativeKernel((const void*)mega_kernel,
                                   dim3(512), dim3(256), margs, 0, stream);
    }

    // 4) out = y @ W_out  (M=2048, N=1024, K=2048)
    gemm_out64<<<dim3(16, 16), 256, 0, stream>>>(ybf, woutT, out, 2048, 1024, 2048);
}

// Round 9
// 265.019 us; speedup vs baseline: 2.1662x; 2.1662x over previous
//
#include <hip/hip_runtime.h>

// ---------------------------------------------------------------------------
// MambaBlock fused pipeline, MI355X (gfx950) — round 9
// B=2, L=1024, D_MODEL=1024, D_INNER=2048, D_STATE=16, D_CONV=4, DT_RANK=64
//
// Round 8's cooperative grid.sync cost ~70 µs/sync (408 µs mega kernel) —
// cross-workgroup sync is dead on this part. Round 9 = round 7 (263 µs, best)
// with conv+silu fused into the skinny GEMM's A-staging (no cross-block dep:
// xz is complete before launch). 9 -> 8 dispatches.
//   * gemm_skinny_conv: computes u = silu(conv(xz)) in registers while
//     staging A; n0==0 blocks also write ucbf for the scan passes.
//   * everything else byte-identical to round 7.
// ---------------------------------------------------------------------------

typedef unsigned short u16;
typedef unsigned int   u32;

#define B_SZ 2
#define L_SZ 1024
#define DM   1024
#define DI   2048
#define DS   16
#define DTR  64
#define NXD  96      /* DTR + 2*DS */
#define NCHUNK 32
#define CL   32      /* chunk length: NCHUNK*CL = L */
#define KSPLIT 8     /* split-K for skinny x_dbl GEMM */
#define KC     256   /* 2048 / KSPLIT */

typedef __bf16 bf16x8 __attribute__((ext_vector_type(8)));
typedef float  f32x4  __attribute__((ext_vector_type(4)));

__device__ __forceinline__ u16 f2bf(float f) {
    u32 x = __float_as_uint(f);
    x += 0x7fffu + ((x >> 16) & 1u);   // round-to-nearest-even
    return (u16)(x >> 16);
}
__device__ __forceinline__ float bf2f(u16 v) {
    return __uint_as_float(((u32)v) << 16);
}

__device__ __forceinline__ void gld_lds16(const u16* g, u16* l) {
    __builtin_amdgcn_global_load_lds(
        (const __attribute__((address_space(1))) u32*)g,
        (__attribute__((address_space(3))) u32*)l, 16, 0, 0);
}

// raw workgroup barrier WITHOUT the compiler's vmcnt(0) drain
__device__ __forceinline__ void wg_barrier() {
    __asm__ volatile("" ::: "memory");
    __builtin_amdgcn_s_barrier();
    __asm__ volatile("" ::: "memory");
}
#define WAIT_VM12() __builtin_amdgcn_s_waitcnt(0xF7C)
#define WAIT_VM9()  __builtin_amdgcn_s_waitcnt(0xF79)
#define WAIT_VM8()  __builtin_amdgcn_s_waitcnt(0xF78)
#define WAIT_VM6()  __builtin_amdgcn_s_waitcnt(0xF76)
#define WAIT_VM4()  __builtin_amdgcn_s_waitcnt(0xF74)
#define WAIT_VM3()  __builtin_amdgcn_s_waitcnt(0xF73)
#define WAIT_VM0()  __builtin_amdgcn_s_waitcnt(0xF70)

// ---------------------------------------------------------------------------
// Pipelined 128x128 GEMM (proven): C = A[M,K]*BT[N,K]^T, BK=32, 4-buf ring,
// prefetch distance 3. op==2: Cb bf16 out.
// ---------------------------------------------------------------------------
__global__ __launch_bounds__(256) void gemm128p(
    const u16* __restrict__ A, const u16* __restrict__ BT,
    float* __restrict__ Cf, u16* __restrict__ Cb,
    int M, int N, int K, int op)
{
    __shared__ u16 As[4][128 * 32];
    __shared__ u16 Bs[4][128 * 32];

    const int tid  = threadIdx.x;
    const int wave = tid >> 6;
    const int lane = tid & 63;
    const int q    = lane >> 4;
    const int r16  = lane & 15;
    const int wm   = (wave & 1) * 64;
    const int wn   = (wave >> 1) * 64;
    const int m0   = blockIdx.y * 128;
    const int n0   = blockIdx.x * 128;

    const u16* gA0 = A  + (size_t)(m0 + (tid >> 2))      * K + (tid & 3) * 8;
    const u16* gA1 = A  + (size_t)(m0 + 64 + (tid >> 2)) * K + (tid & 3) * 8;
    const u16* gB0 = BT + (size_t)(n0 + (tid >> 2))      * K + (tid & 3) * 8;
    const u16* gB1 = BT + (size_t)(n0 + 64 + (tid >> 2)) * K + (tid & 3) * 8;

    const int niter = K >> 5;
    const int pre = niter < 3 ? niter : 3;
    for (int p = 0; p < pre; ++p) {
        const int k0 = p * 32;
        gld_lds16(gA0 + k0, &As[p][tid * 8]);
        gld_lds16(gA1 + k0, &As[p][2048 + tid * 8]);
        gld_lds16(gB0 + k0, &Bs[p][tid * 8]);
        gld_lds16(gB1 + k0, &Bs[p][2048 + tid * 8]);
    }

    f32x4 acc[4][4];
#pragma unroll
    for (int s = 0; s < 4; ++s)
#pragma unroll
        for (int j = 0; j < 4; ++j) acc[s][j] = (f32x4){0.f, 0.f, 0.f, 0.f};

    for (int it = 0; it < niter; ++it) {
        if (it + 3 < niter) {
            const int k0 = (it + 3) * 32;
            const int bi = (it + 3) & 3;
            gld_lds16(gA0 + k0, &As[bi][tid * 8]);
            gld_lds16(gA1 + k0, &As[bi][2048 + tid * 8]);
            gld_lds16(gB0 + k0, &Bs[bi][tid * 8]);
            gld_lds16(gB1 + k0, &Bs[bi][2048 + tid * 8]);
            WAIT_VM12();
        } else if (it + 2 < niter) {
            WAIT_VM8();
        } else if (it + 1 < niter) {
            WAIT_VM4();
        } else {
            WAIT_VM0();
        }
        wg_barrier();

        const int cur = it & 3;
        bf16x8 af[4], bfr[4];
#pragma unroll
        for (int s = 0; s < 4; ++s)
            af[s] = *(const bf16x8*)(&As[cur][(wm + s * 16 + r16) * 32 + q * 8]);
#pragma unroll
        for (int j = 0; j < 4; ++j)
            bfr[j] = *(const bf16x8*)(&Bs[cur][(wn + j * 16 + r16) * 32 + q * 8]);
#pragma unroll
        for (int s = 0; s < 4; ++s)
#pragma unroll
            for (int j = 0; j < 4; ++j)
                acc[s][j] = __builtin_amdgcn_mfma_f32_16x16x32_bf16(
                    af[s], bfr[j], acc[s][j], 0, 0, 0);

        wg_barrier();
    }

#pragma unroll
    for (int s = 0; s < 4; ++s) {
        const int row0 = m0 + wm + s * 16 + q * 4;
#pragma unroll
        for (int j = 0; j < 4; ++j) {
            const int col = n0 + wn + j * 16 + r16;
            if (op == 2) {
#pragma unroll
                for (int i = 0; i < 4; ++i)
                    Cb[(size_t)(row0 + i) * N + col] = f2bf(acc[s][j][i]);
            } else {
#pragma unroll
                for (int i = 0; i < 4; ++i)
                    Cf[(size_t)(row0 + i) * N + col] = acc[s][j][i];
            }
        }
    }
}

// ---------------------------------------------------------------------------
// GEMM-out (proven round 7): 128x64 tile, no split-K, direct fp32.
// ---------------------------------------------------------------------------
__global__ __launch_bounds__(256) void gemm_out64(
    const u16* __restrict__ A, const u16* __restrict__ BT,
    float* __restrict__ C, int M, int N, int K)
{
    __shared__ u16 As[4][128 * 32];
    __shared__ u16 Bs[4][64 * 32];

    const int tid  = threadIdx.x;
    const int wave = tid >> 6;
    const int lane = tid & 63;
    const int q    = lane >> 4;
    const int r16  = lane & 15;
    const int wm   = (wave & 1) * 64;
    const int wn   = (wave >> 1) * 32;
    const int m0   = blockIdx.y * 128;
    const int n0   = blockIdx.x * 64;

    const u16* gA0 = A  + (size_t)(m0 + (tid >> 2))      * K + (tid & 3) * 8;
    const u16* gA1 = A  + (size_t)(m0 + 64 + (tid >> 2)) * K + (tid & 3) * 8;
    const u16* gB0 = BT + (size_t)(n0 + (tid >> 2))      * K + (tid & 3) * 8;

    const int niter = K >> 5;
    const int pre = niter < 3 ? niter : 3;
    for (int p = 0; p < pre; ++p) {
        const int k0 = p * 32;
        gld_lds16(gA0 + k0, &As[p][tid * 8]);
        gld_lds16(gA1 + k0, &As[p][2048 + tid * 8]);
        gld_lds16(gB0 + k0, &Bs[p][tid * 8]);
    }

    f32x4 acc[4][2];
#pragma unroll
    for (int s = 0; s < 4; ++s)
#pragma unroll
        for (int j = 0; j < 2; ++j) acc[s][j] = (f32x4){0.f, 0.f, 0.f, 0.f};

    for (int it = 0; it < niter; ++it) {
        if (it + 3 < niter) {
            const int k0 = (it + 3) * 32;
            const int bi = (it + 3) & 3;
            gld_lds16(gA0 + k0, &As[bi][tid * 8]);
            gld_lds16(gA1 + k0, &As[bi][2048 + tid * 8]);
            gld_lds16(gB0 + k0, &Bs[bi][tid * 8]);
            WAIT_VM9();
        } else if (it + 2 < niter) {
            WAIT_VM6();
        } else if (it + 1 < niter) {
            WAIT_VM3();
        } else {
            WAIT_VM0();
        }
        wg_barrier();

        const int cur = it & 3;
        bf16x8 af[4], bfr[2];
#pragma unroll
        for (int s = 0; s < 4; ++s)
            af[s] = *(const bf16x8*)(&As[cur][(wm + s * 16 + r16) * 32 + q * 8]);
#pragma unroll
        for (int j = 0; j < 2; ++j)
            bfr[j] = *(const bf16x8*)(&Bs[cur][(wn + j * 16 + r16) * 32 + q * 8]);
#pragma unroll
        for (int s = 0; s < 4; ++s)
#pragma unroll
            for (int j = 0; j < 2; ++j)
                acc[s][j] = __builtin_amdgcn_mfma_f32_16x16x32_bf16(
                    af[s], bfr[j], acc[s][j], 0, 0, 0);

        wg_barrier();
    }

#pragma unroll
    for (int s = 0; s < 4; ++s) {
        const int row0 = m0 + wm + s * 16 + q * 4;
#pragma unroll
        for (int j = 0; j < 2; ++j) {
            const int col = n0 + wn + j * 16 + r16;
#pragma unroll
            for (int i = 0; i < 4; ++i)
                C[(size_t)(row0 + i) * N + col] = acc[s][j][i];
        }
    }
}

// ---------------------------------------------------------------------------
// Skinny-N split-K GEMM with FUSED causal conv + silu.
// A[m][k] = u[pos=m][d=k] = silu(sum_j xz[pos+j-3][d]*cw[d][j] + cb[d]),
// computed in registers during staging from xzbf (complete before launch).
// n0==0 blocks also store the u-tile to ucbf (consumed by scan passes).
// Epilogue: atomicAdd into xdbl (zeroed by prep).
// ---------------------------------------------------------------------------
__global__ __launch_bounds__(256) void gemm_skinny_conv(
    const u16* __restrict__ xzbf, const float* __restrict__ cw,
    const float* __restrict__ cb, const u16* __restrict__ BT,
    float* xdbl, u16* __restrict__ ucbf)
{
    constexpr int LDT = 40;
    __shared__ u16 As[128 * LDT];
    __shared__ u16 Bs[64 * LDT];

    const int tid  = threadIdx.x;
    const int wave = tid >> 6;
    const int lane = tid & 63;
    const int q    = lane >> 4;
    const int r16  = lane & 15;
    const int m0   = blockIdx.y * 128;
    const int n0   = blockIdx.x * 64;
    const int kcs  = blockIdx.z * KC;
    const int sr   = tid >> 2;
    const int ss   = (tid & 3) * 8;

    f32x4 acc[2][4];
#pragma unroll
    for (int s = 0; s < 2; ++s)
#pragma unroll
        for (int j = 0; j < 4; ++j) acc[s][j] = (f32x4){0.f, 0.f, 0.f, 0.f};

    const int bcol  = n0 + sr;
    const int bcolc = bcol < NXD ? bcol : NXD - 1;   // clamp; garbage cols dropped

    constexpr int NIT = KC / 32;
    for (int it = 0; it < NIT; ++it) {
        const int c = kcs + it * 32 + ss;            // d-column base (8 wide)
        __syncthreads();

        // per-iter filter taps for the 8 d-columns (coalesced, L1-hot)
        f32x4 cwv[8];
        float cbv[8];
#pragma unroll
        for (int j = 0; j < 8; ++j) {
            cwv[j] = *(const f32x4*)(cw + (size_t)(c + j) * 4);
            cbv[j] = cb[c + j];
        }

        // compute u for rows (m0+sr) and (m0+64+sr), store to LDS (+ucbf)
        uint4 ua[2];
#pragma unroll
        for (int rsel = 0; rsel < 2; ++rsel) {
            const int r = m0 + rsel * 64 + sr;
            const int l = r & (L_SZ - 1);
            float s8[8];
#pragma unroll
            for (int j = 0; j < 8; ++j) s8[j] = cbv[j];
#pragma unroll
            for (int k = 0; k < 4; ++k) {
                if (l + k - 3 >= 0) {
                    uint4 xv = *(const uint4*)(xzbf + (size_t)(r + k - 3) * (2 * DI) + c);
                    const u16* xp = (const u16*)&xv;
#pragma unroll
                    for (int j = 0; j < 8; ++j) {
                        const float w = (k == 0) ? cwv[j].x : (k == 1) ? cwv[j].y
                                       : (k == 2) ? cwv[j].z : cwv[j].w;
                        s8[j] = fmaf(bf2f(xp[j]), w, s8[j]);
                    }
                }
            }
            u16* up = (u16*)&ua[rsel];
#pragma unroll
            for (int j = 0; j < 8; ++j) {
                float v = s8[j] / (1.f + __expf(-s8[j]));
                up[j] = f2bf(v);
            }
        }
        *(uint4*)(As + sr * LDT + ss)        = ua[0];
        *(uint4*)(As + (64 + sr) * LDT + ss) = ua[1];
        if (n0 == 0) {
            *(uint4*)(ucbf + (size_t)(m0 + sr) * DI + c)      = ua[0];
            *(uint4*)(ucbf + (size_t)(m0 + 64 + sr) * DI + c) = ua[1];
        }
        *(uint4*)(Bs + sr * LDT + ss) =
            *(const uint4*)(BT + (size_t)bcolc * DI + kcs + it * 32 + ss);
        __syncthreads();

        bf16x8 af[2], bfr[4];
#pragma unroll
        for (int s = 0; s < 2; ++s)
            af[s] = *(const bf16x8*)(As + (wave * 32 + s * 16 + r16) * LDT + q * 8);
#pragma unroll
        for (int j = 0; j < 4; ++j)
            bfr[j] = *(const bf16x8*)(Bs + (j * 16 + r16) * LDT + q * 8);
#pragma unroll
        for (int s = 0; s < 2; ++s)
#pragma unroll
            for (int j = 0; j < 4; ++j)
                acc[s][j] = __builtin_amdgcn_mfma_f32_16x16x32_bf16(
                    af[s], bfr[j], acc[s][j], 0, 0, 0);
    }

#pragma unroll
    for (int s = 0; s < 2; ++s) {
        const int row0 = m0 + wave * 32 + s * 16 + q * 4;
#pragma unroll
        for (int j = 0; j < 4; ++j) {
            const int col = n0 + j * 16 + r16;
            if (col < NXD) {
#pragma unroll
                for (int i = 0; i < 4; ++i)
                    atomicAdd(&xdbl[(size_t)(row0 + i) * NXD + col], acc[s][j][i]);
            }
        }
    }
}

// ---------------------------------------------------------------------------
// delta GEMM: dlt[2048,2048] = softplus(xdbl[:, :64] @ wdtT^T + b_dt)
// A staged from fp32 xdbl (stride NXD) with on-the-fly bf16 cast; K=64.
// ---------------------------------------------------------------------------
__global__ __launch_bounds__(256) void gemm_delta(
    const float* __restrict__ xdbl, const u16* __restrict__ BT,
    const float* __restrict__ bias, float* __restrict__ dlt)
{
    constexpr int LDT = 40;
    __shared__ u16 As[128 * LDT];
    __shared__ u16 Bs[128 * LDT];

    const int tid  = threadIdx.x;
    const int wave = tid >> 6;
    const int lane = tid & 63;
    const int q    = lane >> 4;
    const int r16  = lane & 15;
    const int wm   = (wave & 1) * 64;
    const int wn   = (wave >> 1) * 64;
    const int m0   = blockIdx.y * 128;
    const int n0   = blockIdx.x * 128;
    const int sr   = tid >> 2;
    const int ss   = (tid & 3) * 8;

    f32x4 acc[4][4];
#pragma unroll
    for (int s = 0; s < 4; ++s)
#pragma unroll
        for (int j = 0; j < 4; ++j) acc[s][j] = (f32x4){0.f, 0.f, 0.f, 0.f};

    for (int k0 = 0; k0 < DTR; k0 += 32) {
        __syncthreads();
        f32x4 f0 = *(const f32x4*)(xdbl + (size_t)(m0 + sr) * NXD + k0 + ss);
        f32x4 f1 = *(const f32x4*)(xdbl + (size_t)(m0 + sr) * NXD + k0 + ss + 4);
        f32x4 f2 = *(const f32x4*)(xdbl + (size_t)(m0 + 64 + sr) * NXD + k0 + ss);
        f32x4 f3 = *(const f32x4*)(xdbl + (size_t)(m0 + 64 + sr) * NXD + k0 + ss + 4);
        uint4 bv0 = *(const uint4*)(BT + (size_t)(n0 + sr)      * DTR + k0 + ss);
        uint4 bv1 = *(const uint4*)(BT + (size_t)(n0 + 64 + sr) * DTR + k0 + ss);
        u16* pa0 = As + sr * LDT + ss;
        u16* pa1 = As + (64 + sr) * LDT + ss;
#pragma unroll
        for (int i = 0; i < 4; ++i) { pa0[i] = f2bf(f0[i]); pa0[4 + i] = f2bf(f1[i]); }
#pragma unroll
        for (int i = 0; i < 4; ++i) { pa1[i] = f2bf(f2[i]); pa1[4 + i] = f2bf(f3[i]); }
        *(uint4*)(Bs + sr * LDT + ss)        = bv0;
        *(uint4*)(Bs + (64 + sr) * LDT + ss) = bv1;
        __syncthreads();

        bf16x8 af[4], bfr[4];
#pragma unroll
        for (int s = 0; s < 4; ++s)
            af[s] = *(const bf16x8*)(As + (wm + s * 16 + r16) * LDT + q * 8);
#pragma unroll
        for (int j = 0; j < 4; ++j)
            bfr[j] = *(const bf16x8*)(Bs + (wn + j * 16 + r16) * LDT + q * 8);
#pragma unroll
        for (int s = 0; s < 4; ++s)
#pragma unroll
            for (int j = 0; j < 4; ++j)
                acc[s][j] = __builtin_amdgcn_mfma_f32_16x16x32_bf16(
                    af[s], bfr[j], acc[s][j], 0, 0, 0);
    }

#pragma unroll
    for (int s = 0; s < 4; ++s) {
        const int row0 = m0 + wm + s * 16 + q * 4;
#pragma unroll
        for (int j = 0; j < 4; ++j) {
            const int col = n0 + wn + j * 16 + r16;
            const float bv = bias[col];
#pragma unroll
            for (int i = 0; i < 4; ++i) {
                float v = acc[s][j][i] + bv;
                v = (v > 20.f) ? v : log1pf(__expf(v));
                dlt[(size_t)(row0 + i) * DI + col] = v;
            }
        }
    }
}

// ---------------------------------------------------------------------------
// fused prep: x cast + 4 weight transposes + zero xdbl (for atomics)
// ---------------------------------------------------------------------------
__device__ __forceinline__ void tr_tile(
    const float* __restrict__ in, u16* __restrict__ out,
    int R, int C, int tr, int tc, int tid, float (*t)[33])
{
    const int tx = tid & 31, ty = tid >> 5;
    const int r0 = tr * 32, c0 = tc * 32;
#pragma unroll
    for (int i = 0; i < 4; ++i) {
        int r = r0 + ty + i * 8, c = c0 + tx;
        if (r < R && c < C) t[ty + i * 8][tx] = in[(size_t)r * C + c];
    }
    __syncthreads();
#pragma unroll
    for (int i = 0; i < 4; ++i) {
        int oR = c0 + ty + i * 8, oC = r0 + tx;
        if (oR < C && oC < R) out[(size_t)oR * R + oC] = f2bf(t[tx][ty + i * 8]);
    }
}

__global__ __launch_bounds__(256) void prep_kernel(
    const float* __restrict__ x,     u16* __restrict__ xbf,
    const float* __restrict__ W_in,  u16* __restrict__ winT,
    const float* __restrict__ W_out, u16* __restrict__ woutT,
    const float* __restrict__ W_x,   u16* __restrict__ wxT,
    const float* __restrict__ W_dt,  u16* __restrict__ wdtT,
    float* __restrict__ xdbl)
{
    __shared__ float t[32][33];
    const int id  = blockIdx.x;
    const int tid = threadIdx.x;
    if (id < 4096) {                                   // W_in: 1024x4096
        tr_tile(W_in, winT, 1024, 4096, id >> 7, id & 127, tid, t);
    } else if (id < 6144) {                            // W_out: 2048x1024
        int i2 = id - 4096;
        tr_tile(W_out, woutT, 2048, 1024, i2 >> 5, i2 & 31, tid, t);
    } else if (id < 6336) {                            // W_x: 2048x96
        int i3 = id - 6144;
        tr_tile(W_x, wxT, 2048, 96, i3 / 3, i3 % 3, tid, t);
    } else if (id < 6464) {                            // W_dt: 64x2048
        int i4 = id - 6336;
        tr_tile(W_dt, wdtT, 64, 2048, i4 >> 6, i4 & 63, tid, t);
    } else if (id < 14656) {                           // x cast: 2,097,152
        int i = (id - 6464) * 256 + tid;
        xbf[i] = f2bf(x[i]);
    } else {                                           // zero xdbl: 196,608 f
        f32x4 z = (f32x4){0.f, 0.f, 0.f, 0.f};
        ((f32x4*)xdbl)[(size_t)(id - 14656) * 256 + tid] = z;
    }
}

// ---------------------------------------------------------------------------
// Selective scan, 3-pass chunked, NCHUNK=32 (2 blocks/CU).
// ---------------------------------------------------------------------------
__global__ __launch_bounds__(256) void scan_pass1(
    const float* __restrict__ delta, const u16* __restrict__ ucbf,
    const float* __restrict__ xdbl, const float* __restrict__ A_log,
    float* __restrict__ hbuf, float* __restrict__ pbuf)
{
    const int c = blockIdx.x;
    const int d = blockIdx.y * 256 + threadIdx.x;
    const int b = blockIdx.z;
    float Av[16], h[16], P[16];
#pragma unroll
    for (int n = 0; n < 16; ++n) {
        Av[n] = -__expf(A_log[d * 16 + n]);
        h[n] = 0.f; P[n] = 1.f;
    }
    const int rowbase = b * L_SZ + c * CL;
    for (int i = 0; i < CL; ++i) {
        const int row = rowbase + i;
        float dlt = delta[(size_t)row * DI + d];
        float uu  = bf2f(ucbf[(size_t)row * DI + d]);
        float du  = dlt * uu;
        const float* xr = xdbl + (size_t)row * NXD;   // block-uniform address
#pragma unroll
        for (int n = 0; n < 16; ++n) {
            float e = __expf(dlt * Av[n]);
            P[n] *= e;
            h[n] = fmaf(e, h[n], du * xr[DTR + n]);
        }
    }
    size_t base = ((size_t)((b * NCHUNK + c) * DI + d)) * 16;
#pragma unroll
    for (int n = 0; n < 16; ++n) { hbuf[base + n] = h[n]; pbuf[base + n] = P[n]; }
}

// parallel over (b, d*16+n): coalesced
__global__ __launch_bounds__(256) void scan_pass2(
    float* __restrict__ hbuf, const float* __restrict__ pbuf)
{
    const int j = blockIdx.x * 256 + threadIdx.x;   // d*16+n in [0, 32768)
    const int b = blockIdx.y;
    float h0 = 0.f;
    for (int cc = 0; cc < NCHUNK; ++cc) {
        size_t o = ((size_t)(b * NCHUNK + cc)) * (DI * 16) + j;
        float hl = hbuf[o];
        float Pl = pbuf[o];
        hbuf[o] = h0;                  // h0 entering chunk cc
        h0 = fmaf(Pl, h0, hl);
    }
}

__global__ __launch_bounds__(256) void scan_pass3(
    const float* __restrict__ delta, const u16* __restrict__ ucbf,
    const float* __restrict__ xdbl, const float* __restrict__ A_log,
    const float* __restrict__ hbuf, const u16* __restrict__ xzbf,
    const float* __restrict__ Dskip, u16* __restrict__ ybf)
{
    const int c = blockIdx.x;
    const int d = blockIdx.y * 256 + threadIdx.x;
    const int b = blockIdx.z;
    float Av[16], h[16];
    size_t base = ((size_t)((b * NCHUNK + c) * DI + d)) * 16;
#pragma unroll
    for (int n = 0; n < 16; ++n) {
        Av[n] = -__expf(A_log[d * 16 + n]);
        h[n]  = hbuf[base + n];
    }
    const float Dk = Dskip[d];
    const int rowbase = b * L_SZ + c * CL;
    for (int i = 0; i < CL; ++i) {
        const int row = rowbase + i;
        float dlt = delta[(size_t)row * DI + d];
        float uu  = bf2f(ucbf[(size_t)row * DI + d]);
        float du  = dlt * uu;
        const float* xr = xdbl + (size_t)row * NXD;
        float y = 0.f;
#pragma unroll
        for (int n = 0; n < 16; ++n) {
            float e = __expf(dlt * Av[n]);
            h[n] = fmaf(e, h[n], du * xr[DTR + n]);
            y = fmaf(h[n], xr[DTR + DS + n], y);
        }
        float zz = bf2f(xzbf[(size_t)row * (2 * DI) + DI + d]);
        float yv = fmaf(uu, Dk, y) * (zz / (1.f + __expf(-zz)));
        ybf[(size_t)row * DI + d] = f2bf(yv);
    }
}

// ---------------------------------------------------------------------------
// workspace layout (f32 element offsets)
// ---------------------------------------------------------------------------
constexpr size_t OFF_DELTA   = 0;                          // 4,194,304 f
constexpr size_t OFF_XDBL    = OFF_DELTA + 4194304;        //   196,608 f
constexpr size_t OFF_HBUF    = OFF_XDBL  + 196608;         // 2,097,152 f
constexpr size_t OFF_PBUF    = OFF_HBUF  + 2097152;        // 2,097,152 f
constexpr size_t OFF_F32_END = OFF_PBUF  + 2097152;
// bf16 region (u16 offsets from end of fp32 region)
constexpr size_t SOFF_XBF   = 0;                     // 2,097,152
constexpr size_t SOFF_WINT  = SOFF_XBF   + 2097152;  // 4,194,304
constexpr size_t SOFF_XZBF  = SOFF_WINT  + 4194304;  // 8,388,608
constexpr size_t SOFF_UCBF  = SOFF_XZBF  + 8388608;  // 4,194,304
constexpr size_t SOFF_WXT   = SOFF_UCBF  + 4194304;  //   196,608
constexpr size_t SOFF_WDTT  = SOFF_WXT   + 196608;   //   131,072
constexpr size_t SOFF_WOUTT = SOFF_WDTT  + 131072;   // 2,097,152
constexpr size_t SOFF_YBF   = SOFF_WOUTT + 2097152;  // 4,194,304

extern "C" void kernel_launch(void* const* d_in, const int* in_sizes, int n_in,
                              void* d_out, int out_size, void* d_ws, size_t ws_size,
                              hipStream_t stream)
{
    const float* x     = (const float*)d_in[0];
    const float* W_in  = (const float*)d_in[1];
    const float* cw    = (const float*)d_in[2];
    const float* cb    = (const float*)d_in[3];
    const float* W_x   = (const float*)d_in[4];
    const float* W_dt  = (const float*)d_in[5];
    const float* b_dt  = (const float*)d_in[6];
    const float* A_log = (const float*)d_in[7];
    const float* Dsk   = (const float*)d_in[8];
    const float* W_out = (const float*)d_in[9];
    float* out = (float*)d_out;

    float* wsf   = (float*)d_ws;
    float* dlt   = wsf + OFF_DELTA;
    float* xdbl  = wsf + OFF_XDBL;
    float* hbuf  = wsf + OFF_HBUF;
    float* pbuf  = wsf + OFF_PBUF;
    u16* sb    = (u16*)(wsf + OFF_F32_END);
    u16* xbf   = sb + SOFF_XBF;
    u16* winT  = sb + SOFF_WINT;
    u16* xzbf  = sb + SOFF_XZBF;
    u16* ucbf  = sb + SOFF_UCBF;
    u16* wxT   = sb + SOFF_WXT;
    u16* wdtT  = sb + SOFF_WDTT;
    u16* woutT = sb + SOFF_WOUTT;
    u16* ybf   = sb + SOFF_YBF;

    // 1) fused prep (casts, transposes, xdbl zero)
    prep_kernel<<<14848, 256, 0, stream>>>(x, xbf, W_in, winT, W_out, woutT,
                                           W_x, wxT, W_dt, wdtT, xdbl);

    // 2) xz = x @ W_in  (M=2048, N=4096, K=1024) -> bf16
    gemm128p<<<dim3(32, 16), 256, 0, stream>>>(
        xbf, winT, nullptr, xzbf, 2048, 4096, 1024, 2);

    // 3) x_dbl = silu(conv(xz)) @ W_x — conv fused into staging; atomics to xdbl
    gemm_skinny_conv<<<dim3(2, 16, KSPLIT), 256, 0, stream>>>(
        xzbf, cw, cb, wxT, xdbl, ucbf);

    // 4) delta = softplus(xdbl[:, :64] @ W_dt + b_dt) -> dlt fp32
    gemm_delta<<<dim3(16, 16), 256, 0, stream>>>(xdbl, wdtT, b_dt, dlt);

    // 5) selective scan (3-pass chunked, NCHUNK=32)
    scan_pass1<<<dim3(NCHUNK, DI / 256, B_SZ), 256, 0, stream>>>(dlt, ucbf, xdbl, A_log, hbuf, pbuf);
    scan_pass2<<<dim3(DI * 16 / 256, B_SZ), 256, 0, stream>>>(hbuf, pbuf);
    scan_pass3<<<dim3(NCHUNK, DI / 256, B_SZ), 256, 0, stream>>>(dlt, ucbf, xdbl, A_log, hbuf, xzbf, Dsk, ybf);

    // 6) out = y @ W_out  (M=2048, N=1024, K=2048) — single kernel, direct fp32
    gemm_out64<<<dim3(16, 16), 256, 0, stream>>>(ybf, woutT, out, 2048, 1024, 2048);
}